// Round 5
// baseline (5884.165 us; speedup 1.0000x reference)
//
#include <hip/hip_runtime.h>
#include <hip/hip_bf16.h>

#define T_STEPS 256
#define BATCH 64
#define HID 512
#define NLAYERS 4
#define BT_GROUPS 4
#define GBLK 16            // blocks per bt-group (each owns 32 h-cols)
#define SCAN_THREADS 256
#define ASTRIDE 1032       // padded LDS k-stride (shorts)
#define GLSTR 164          // gl float stride (160 cols + pad)

typedef __bf16 bf16_t;
typedef __attribute__((ext_vector_type(8))) __bf16 bf16x8;
typedef __attribute__((ext_vector_type(4))) float f32x4;
typedef __attribute__((ext_vector_type(4))) unsigned int u32x4;

__device__ __forceinline__ float sigm(float x){ return 1.0f/(1.0f + __expf(-x)); }
__device__ __forceinline__ float tanh_f(float x){ return 2.0f/(1.0f + __expf(-2.0f*x)) - 1.0f; }
__device__ __forceinline__ unsigned short f2bf(float x){ __bf16 b=(__bf16)x; return __builtin_bit_cast(unsigned short, b); }
__device__ __forceinline__ float bf2f(unsigned int u){ return __builtin_bit_cast(float, u<<16); }

// ---- transpose fp32 [R][C] -> bf16 [C][R] ----
__global__ void transpose_cast_kernel(const float* __restrict__ src, unsigned short* __restrict__ dst, int R, int C){
  __shared__ float tile[32][33];
  int tx = threadIdx.x & 31, ty = threadIdx.x >> 5;
  int c0 = blockIdx.x*32, r0 = blockIdx.y*32;
  #pragma unroll
  for(int i=0;i<4;i++){ int r = r0 + ty + i*8; tile[ty+i*8][tx] = src[(size_t)r*C + c0 + tx]; }
  __syncthreads();
  #pragma unroll
  for(int i=0;i<4;i++){ int c = c0 + ty + i*8; dst[(size_t)c*R + r0 + tx] = f2bf(tile[tx][ty+i*8]); }
}

// ---- inputs (B,T,D) fp32 -> masked bf16 (T,B,D) ----
__global__ void prep_x0_kernel(const float* __restrict__ inp, const int* __restrict__ lens, unsigned short* __restrict__ x0){
  int idx = blockIdx.x*blockDim.x + threadIdx.x;
  int e = idx*4;
  int d = e & (HID-1);
  int tb = e >> 9;
  int b = tb & (BATCH-1);
  int t = tb >> 6;
  const float4 v = *(const float4*)(inp + ((size_t)b*T_STEPS + t)*HID + d);
  float m = (t < lens[b]) ? 1.f : 0.f;
  ushort4 u; u.x=f2bf(v.x*m); u.y=f2bf(v.y*m); u.z=f2bf(v.z*m); u.w=f2bf(v.w*m);
  *(ushort4*)(x0 + ((size_t)t*BATCH + b)*HID + d) = u;
}

// ---- lin precompute: Lin[m][n] = X[m][:] @ WlinT[n][:]  (m = t*B+b, n = 512 lin cols) ----
__global__ void lin_gemm_kernel(const unsigned short* __restrict__ X,
                                const unsigned short* __restrict__ WlinT,
                                unsigned short* __restrict__ Lin){
  int lane = threadIdx.x & 63, wv = threadIdx.x >> 6;
  int frow = lane & 15, quad = lane >> 4;
  int m0 = (blockIdx.x >> 3) * 16;
  int n0 = (blockIdx.x & 7) * 64 + wv*16;
  const bf16_t* arow = (const bf16_t*)X + (size_t)(m0+frow)*HID + quad*8;
  const bf16_t* brow = (const bf16_t*)WlinT + (size_t)(n0+frow)*HID + quad*8;
  f32x4 acc = {0.f,0.f,0.f,0.f};
  #pragma unroll
  for(int kk=0;kk<16;kk++){
    bf16x8 a = *(const bf16x8*)(arow + kk*32);
    bf16x8 b = *(const bf16x8*)(brow + kk*32);
    acc = __builtin_amdgcn_mfma_f32_16x16x32_bf16(a,b,acc,0,0,0);
  }
  #pragma unroll
  for(int r4=0;r4<4;r4++){
    int m = m0 + quad*4 + r4, n = n0 + frow;
    Lin[(size_t)m*HID + n] = f2bf(acc[r4]);
  }
}

// ---- fused per-layer scan ----
// block (bt,g): batch rows bt*16..+15, h-cols g*32..+31 (5 gates x 32 = 160 gate cols = 10 MFMA n-tiles)
// Weights register-resident; wave w handles ksteps == w (mod 4); gate partials summed in LDS.
__global__ void __launch_bounds__(SCAN_THREADS,1)
scan_kernel(const unsigned short* __restrict__ xsrc,
            const unsigned short* __restrict__ WihT,   // [3072][512] bf16
            const unsigned short* __restrict__ WhhT,   // [2560][512] bf16
            const unsigned short* __restrict__ Lin,    // [T*B][512] bf16 (precomputed highway lin)
            const float* __restrict__ bias_l,
            const int* __restrict__ lens,
            unsigned short* __restrict__ Hxb,          // [2][64][512] bf16
            int* __restrict__ flags,                   // [4][16] ints (one 64B line per group)
            unsigned short* __restrict__ xdst,         // bf16 (T,B,H), null on last layer
            float* __restrict__ dout,                  // fp32 (B,T,H), last layer only
            int rev)
{
  extern __shared__ char smem[];
  unsigned short* Al = (unsigned short*)smem;          // [16][ASTRIDE]
  float* gl = (float*)(Al + 16*ASTRIDE);               // [4 planes *16 rows][GLSTR]
  float* bl = gl + 64*GLSTR;                           // [160]
  int*   ll = (int*)(bl + 160);                        // [16]
  unsigned short* hl = (unsigned short*)(ll + 16);     // [512]

  const int tid = threadIdx.x;
  const int bt  = blockIdx.x & (BT_GROUPS-1);
  const int g   = blockIdx.x >> 2;                     // 0..15
  const int lane = tid & 63, wv = tid >> 6;
  const int frow = lane & 15, quad = lane >> 4;

  for(int i=tid;i<160;i+=SCAN_THREADS) bl[i] = bias_l[(i>>5)*HID + g*32 + (i&31)];
  if(tid<16) ll[tid] = lens[bt*16+tid];
  __syncthreads();

  // ---- B fragments in registers: 10 tiles x 8 ksteps (kstep = wv + 4j) ----
  bf16x8 Bf[10][8];
  #pragma unroll
  for(int q=0;q<5;q++){
    #pragma unroll
    for(int ch=0;ch<2;ch++){
      const int ft = q*2+ch;
      const size_t gcol = (size_t)(q*HID + g*32 + ch*16 + frow);
      #pragma unroll
      for(int j=0;j<8;j++){
        int k0 = (wv + j*4)*32 + quad*8;
        const unsigned short* src = (j<4) ? (WihT + gcol*HID + k0)
                                          : (WhhT + gcol*HID + (k0-512));
        Bf[ft][j] = *(const bf16x8*)src;
      }
    }
  }

  // combine-thread constants (all 256 threads: 2 h-values each)
  const int cr = tid >> 4;            // row 0..15
  const int jj = (tid & 15)*2;        // col pair
  const int brow_g = bt*16 + cr;
  const int hcol   = g*32 + jj;
  const int L_r = ll[cr];
  float c0=0.f, c1=0.f, h0s=0.f, h1s=0.f;
  unsigned int hpack=0; int tprev=0;

  const int* fp = flags + bt*GBLK + (lane & 15);
  const bf16_t* arow = (const bf16_t*)Al + (size_t)frow*ASTRIDE + quad*8;

  for(int s=0; s<T_STEPS; s++){
    // ---- phase 1: publish h(s-1) [w0] | poll peers [w1] | stage x [w2,w3] ----
    if(wv==0){
      if(s>0){
        int r = lane>>2, c8 = (lane&3)*8;
        u32x4 val = *(const u32x4*)(hl + r*32 + c8);
        const unsigned short* dst = Hxb + (size_t)(s&1)*BATCH*HID + (size_t)(bt*16+r)*HID + g*32 + c8;
        asm volatile("global_store_dwordx4 %0, %1, off sc0 sc1" :: "v"(dst), "v"(val) : "memory");
        asm volatile("s_waitcnt vmcnt(0)" ::: "memory");
        if(lane==0)
          __hip_atomic_store(flags + bt*GBLK + g, s, __ATOMIC_RELAXED, __HIP_MEMORY_SCOPE_AGENT);
        if(dout) *(float2*)(dout + ((size_t)brow_g*T_STEPS + tprev)*HID + hcol) = make_float2(h0s,h1s);
        else     *(unsigned int*)(xdst + ((size_t)tprev*BATCH + brow_g)*HID + hcol) = hpack;
      }
    } else if(wv==1){
      if(s>0){
        if(dout) *(float2*)(dout + ((size_t)brow_g*T_STEPS + tprev)*HID + hcol) = make_float2(h0s,h1s);
        else     *(unsigned int*)(xdst + ((size_t)tprev*BATCH + brow_g)*HID + hcol) = hpack;
        int it = 0;
        while(1){
          int v = __hip_atomic_load(fp, __ATOMIC_RELAXED, __HIP_MEMORY_SCOPE_AGENT);
          if(__all(lane<16 ? (v>=s) : true)) break;
          if(++it > (1<<20)) break;
        }
        asm volatile("" ::: "memory");
      }
    } else {
      if(s>0){
        if(dout) *(float2*)(dout + ((size_t)brow_g*T_STEPS + tprev)*HID + hcol) = make_float2(h0s,h1s);
        else     *(unsigned int*)(xdst + ((size_t)tprev*BATCH + brow_g)*HID + hcol) = hpack;
      }
      int base = tid - 128;  // 0..127
      #pragma unroll
      for(int i=0;i<8;i++){
        int idx = base + i*128;
        int r = idx>>6, c8 = (idx&63)*8;
        int L = ll[r];
        int t = rev ? ((s < L) ? (L-1-s) : s) : s;
        u32x4 v = *(const u32x4*)(xsrc + ((size_t)t*BATCH + bt*16 + r)*HID + c8);
        *(u32x4*)(Al + r*ASTRIDE + c8) = v;
      }
    }
    __syncthreads();   // b1: x staged, h(s) published+visible

    // ---- phase 2: h loads (IC) under x-half MFMA shadow, then regs->LDS ----
    u32x4 hv[4];
    const unsigned short* hbase = Hxb + (size_t)(s&1)*BATCH*HID + (size_t)bt*16*HID;
    #pragma unroll
    for(int i=0;i<4;i++){
      int idx = tid + i*256;
      const unsigned short* p = hbase + (idx>>6)*HID + (idx&63)*8;
      asm volatile("global_load_dwordx4 %0, %1, off sc0 sc1" : "=v"(hv[i]) : "v"(p) : "memory");
    }

    f32x4 acc[10];
    #pragma unroll
    for(int ft=0;ft<10;ft++) acc[ft] = (f32x4){0.f,0.f,0.f,0.f};
    #pragma unroll
    for(int j=0;j<4;j++){
      bf16x8 a = *(const bf16x8*)(arow + (wv + j*4)*32);
      #pragma unroll
      for(int ft=0;ft<10;ft++)
        acc[ft] = __builtin_amdgcn_mfma_f32_16x16x32_bf16(a, Bf[ft][j], acc[ft], 0,0,0);
    }

    asm volatile("s_waitcnt vmcnt(0)" ::: "memory");
    #pragma unroll
    for(int i=0;i<4;i++){
      int idx = tid + i*256;
      *(u32x4*)(Al + (idx>>6)*ASTRIDE + 512 + (idx&63)*8) = hv[i];
    }

    // lin prefetch (plain cached load; consumed in phase 4)
    bool valid = s < L_r;
    int tcur = rev ? (valid ? (L_r-1-s) : s) : s;
    unsigned int linv = *(const unsigned int*)(Lin + ((size_t)tcur*BATCH + brow_g)*HID + hcol);
    __syncthreads();  // b2: h staged

    // ---- phase 3: h-half MFMAs + gate partial writes ----
    #pragma unroll
    for(int j=4;j<8;j++){
      bf16x8 a = *(const bf16x8*)(arow + (wv + j*4)*32);
      #pragma unroll
      for(int ft=0;ft<10;ft++)
        acc[ft] = __builtin_amdgcn_mfma_f32_16x16x32_bf16(a, Bf[ft][j], acc[ft], 0,0,0);
    }
    #pragma unroll
    for(int ft=0;ft<10;ft++){
      #pragma unroll
      for(int r4=0;r4<4;r4++)
        gl[(size_t)(wv*16 + quad*4 + r4)*GLSTR + ft*16 + frow] = acc[ft][r4];
    }
    __syncthreads();  // b3

    // ---- phase 4: combine (all 256 threads, 2 h-values each) ----
    {
      float gax[5], gay[5];
      #pragma unroll
      for(int q=0;q<5;q++){
        float2 sum = *(const float2*)(bl + q*32 + jj);
        #pragma unroll
        for(int w=0;w<4;w++){
          float2 p = *(const float2*)(gl + (size_t)(w*16+cr)*GLSTR + q*32 + jj);
          sum.x += p.x; sum.y += p.y;
        }
        gax[q]=sum.x; gay[q]=sum.y;
      }
      float m = valid ? 1.f : 0.f;
      float lin0 = bf2f(linv & 0xffffu), lin1 = bf2f(linv >> 16);
      float gi0=sigm(gax[0]), gi1=sigm(gay[0]);
      float gf0=sigm(gax[1]), gf1=sigm(gay[1]);
      float gc0=tanh_f(gax[2]), gc1=tanh_f(gay[2]);
      float go0=sigm(gax[3]), go1=sigm(gay[3]);
      float gr0=sigm(gax[4]), gr1=sigm(gay[4]);
      c0 = (gf0*c0 + gi0*gc0) * m;
      c1 = (gf1*c1 + gi1*gc1) * m;
      h0s = (gr0*(go0*tanh_f(c0)) + (1.f-gr0)*lin0) * m;
      h1s = (gr1*(go1*tanh_f(c1)) + (1.f-gr1)*lin1) * m;
      hpack = (unsigned int)f2bf(h0s) | ((unsigned int)f2bf(h1s) << 16);
      *(unsigned int*)(hl + cr*32 + jj) = hpack;
      tprev = tcur;
    }
    __syncthreads();  // b4: hl complete (publish reads it next phase 1)
  }

  // epilogue: outputs for step T-1
  if(dout) *(float2*)(dout + ((size_t)brow_g*T_STEPS + tprev)*HID + hcol) = make_float2(h0s,h1s);
  else     *(unsigned int*)(xdst + ((size_t)tprev*BATCH + brow_g)*HID + hcol) = hpack;
}

#define SMEM_BYTES (16*ASTRIDE*2 + 64*GLSTR*4 + 160*4 + 16*4 + 512*2)

extern "C" void kernel_launch(void* const* d_in, const int* in_sizes, int n_in,
                              void* d_out, int out_size, void* d_ws, size_t ws_size,
                              hipStream_t stream){
  const float* inp    = (const float*)d_in[0];
  const float* weight = (const float*)d_in[1];
  const float* bias   = (const float*)d_in[2];
  const int*   lens   = (const int*)d_in[3];
  float* dout = (float*)d_out;

  char* ws = (char*)d_ws;
  size_t off = 0;
  const size_t WTL = (size_t)(3072+2560)*512;   // per-layer transposed bf16 elements
  unsigned short* WT = (unsigned short*)(ws+off); off += (size_t)NLAYERS*WTL*2;
  unsigned short* x0 = (unsigned short*)(ws+off); off += (size_t)T_STEPS*BATCH*HID*2;
  unsigned short* xA = (unsigned short*)(ws+off); off += (size_t)T_STEPS*BATCH*HID*2;
  unsigned short* xB = (unsigned short*)(ws+off); off += (size_t)T_STEPS*BATCH*HID*2;
  unsigned short* Lin = (unsigned short*)(ws+off); off += (size_t)T_STEPS*BATCH*HID*2;
  unsigned short* Hxb = (unsigned short*)(ws+off); off += (size_t)2*BATCH*HID*2;
  int*   flags= (int*)(ws+off);   off += 1024;

  hipFuncSetAttribute((const void*)scan_kernel, hipFuncAttributeMaxDynamicSharedMemorySize, SMEM_BYTES);

  const size_t WS_L = (size_t)512*3072 + (size_t)512*2560; // per-layer fp32 weight elements
  for(int l=0;l<NLAYERS;l++){
    const float* wih = weight + l*WS_L;
    const float* whh = wih + (size_t)512*3072;
    unsigned short* wihT = WT + l*WTL;
    unsigned short* whhT = wihT + (size_t)3072*512;
    transpose_cast_kernel<<<dim3(3072/32,512/32),256,0,stream>>>(wih, wihT, 512, 3072);
    transpose_cast_kernel<<<dim3(2560/32,512/32),256,0,stream>>>(whh, whhT, 512, 2560);
  }
  prep_x0_kernel<<<8192,256,0,stream>>>(inp, lens, x0);

  unsigned short* bufs[4] = {x0, xA, xB, xA};
  for(int l=0;l<NLAYERS;l++){
    const unsigned short* xin = bufs[l];
    unsigned short* xout = (l<3) ? bufs[l+1] : nullptr;
    const unsigned short* wihT = WT + l*WTL;
    const unsigned short* whhT = wihT + (size_t)3072*512;
    const unsigned short* wlinT = wihT + (size_t)5*512*512;   // lin gate rows of WihT

    lin_gemm_kernel<<<8192,256,0,stream>>>(xin, wlinT, Lin);
    hipMemsetAsync(Hxb, 0, (size_t)2*BATCH*HID*2 + 1024, stream);  // Hxb + flags (adjacent)
    scan_kernel<<<BT_GROUPS*GBLK, SCAN_THREADS, SMEM_BYTES, stream>>>(
        xin, wihT, whhT, Lin,
        bias + (size_t)l*2560, lens, Hxb, flags,
        xout, (l==3) ? dout : nullptr, l&1);
  }
}

// Round 7
// 3471.582 us; speedup vs baseline: 1.6950x; 1.6950x over previous
//
#include <hip/hip_runtime.h>
#include <hip/hip_bf16.h>

#define T_STEPS 256
#define BATCH 64
#define HID 512
#define GATES 3072
#define NLAYERS 4
#define BT_GROUPS 4
#define GBLK 32            // blocks per bt-group (each owns 16 h-cols)
#define SCAN_THREADS 256
#define HSTR 520           // h-tile LDS k-stride (elems); 1040 B, 16B-aligned rows
#define GLP 84             // gl float stride (80 + pad)

typedef __bf16 bf16_t;
typedef _Float16 fp16_t;
typedef __attribute__((ext_vector_type(8))) __bf16 bf16x8;
typedef __attribute__((ext_vector_type(4))) float f32x4;
typedef __attribute__((ext_vector_type(4))) unsigned int u32x4;

__device__ __forceinline__ float sigm(float x){ return 1.0f/(1.0f + __expf(-x)); }
__device__ __forceinline__ float tanh_f(float x){ return 2.0f/(1.0f + __expf(-2.0f*x)) - 1.0f; }
__device__ __forceinline__ unsigned short f2bf(float x){ __bf16 b=(__bf16)x; return __builtin_bit_cast(unsigned short, b); }

// ---- transpose fp32 [R][C] -> bf16 [C][R] ----
__global__ void transpose_cast_kernel(const float* __restrict__ src, unsigned short* __restrict__ dst, int R, int C){
  __shared__ float tile[32][33];
  int tx = threadIdx.x & 31, ty = threadIdx.x >> 5;
  int c0 = blockIdx.x*32, r0 = blockIdx.y*32;
  #pragma unroll
  for(int i=0;i<4;i++){ int r = r0 + ty + i*8; tile[ty+i*8][tx] = src[(size_t)r*C + c0 + tx]; }
  __syncthreads();
  #pragma unroll
  for(int i=0;i<4;i++){ int c = c0 + ty + i*8; dst[(size_t)c*R + r0 + tx] = f2bf(tile[tx][ty+i*8]); }
}

// ---- inputs (B,T,D) fp32 -> masked bf16 (T,B,D) ----
__global__ void prep_x0_kernel(const float* __restrict__ inp, const int* __restrict__ lens, unsigned short* __restrict__ x0){
  int idx = blockIdx.x*blockDim.x + threadIdx.x;
  int e = idx*4;
  int d = e & (HID-1);
  int tb = e >> 9;
  int b = tb & (BATCH-1);
  int t = tb >> 6;
  const float4 v = *(const float4*)(inp + ((size_t)b*T_STEPS + t)*HID + d);
  float m = (t < lens[b]) ? 1.f : 0.f;
  ushort4 u; u.x=f2bf(v.x*m); u.y=f2bf(v.y*m); u.z=f2bf(v.z*m); u.w=f2bf(v.w*m);
  *(ushort4*)(x0 + ((size_t)t*BATCH + b)*HID + d) = u;
}

// ---- xi GEMM: C[m][n] = A[m][:] @ BT[n][:],  M=16384, N=3072, K=512, out fp16 ----
__global__ void __launch_bounds__(256,2)
xi_gemm_kernel(const unsigned short* __restrict__ A,   // [16384][512] bf16
               const unsigned short* __restrict__ BT,  // [3072][512] bf16 (WihT)
               fp16_t* __restrict__ C)                  // [16384][3072] fp16
{
  __shared__ __align__(16) unsigned short As[128*72];
  __shared__ __align__(16) unsigned short Bs[128*72];
  const int tid = threadIdx.x, lane = tid & 63, wv = tid >> 6;
  const int frow = lane & 15, quad = lane >> 4;
  const int m0 = blockIdx.x*128, n0 = blockIdx.y*128;
  const int mh = (wv>>1)*64, nh = (wv&1)*64;
  const int sr = tid>>1, sk = (tid&1)*32;
  f32x4 acc[4][4];
  #pragma unroll
  for(int mt=0;mt<4;mt++)
    #pragma unroll
    for(int nt=0;nt<4;nt++) acc[mt][nt] = (f32x4){0.f,0.f,0.f,0.f};

  for(int kc=0;kc<512;kc+=64){
    // 16-byte chunks: uint4 = 8 shorts; i*8 shorts stride
    #pragma unroll
    for(int i=0;i<4;i++){
      *(uint4*)(As + sr*72 + sk + i*8) = *(const uint4*)(A + (size_t)(m0+sr)*512 + kc + sk + i*8);
      *(uint4*)(Bs + sr*72 + sk + i*8) = *(const uint4*)(BT + (size_t)(n0+sr)*512 + kc + sk + i*8);
    }
    __syncthreads();
    #pragma unroll
    for(int ks=0;ks<2;ks++){
      bf16x8 av[4], bv[4];
      #pragma unroll
      for(int mt=0;mt<4;mt++) av[mt] = *(const bf16x8*)(As + (mh+mt*16+frow)*72 + ks*32 + quad*8);
      #pragma unroll
      for(int nt=0;nt<4;nt++) bv[nt] = *(const bf16x8*)(Bs + (nh+nt*16+frow)*72 + ks*32 + quad*8);
      #pragma unroll
      for(int mt=0;mt<4;mt++)
        #pragma unroll
        for(int nt=0;nt<4;nt++)
          acc[mt][nt] = __builtin_amdgcn_mfma_f32_16x16x32_bf16(av[mt], bv[nt], acc[mt][nt],0,0,0);
    }
    __syncthreads();
  }
  #pragma unroll
  for(int mt=0;mt<4;mt++)
    #pragma unroll
    for(int nt=0;nt<4;nt++)
      #pragma unroll
      for(int r4=0;r4<4;r4++)
        C[(size_t)(m0+mh+mt*16+quad*4+r4)*GATES + n0+nh+nt*16+frow] = (fp16_t)acc[mt][nt][r4];
}

// ---- fused per-layer scan (h-recurrence only; xi precomputed) ----
// block (bt,g): batch rows bt*16..+15, h-cols g*16..+15 (5 gates x 16 = 80 gate cols)
// W_hh slice register-resident: 20 bf16x8/wave (kstep = wv + 4j).
__global__ void __launch_bounds__(SCAN_THREADS,1)
scan_kernel(const fp16_t* __restrict__ Xi,             // [T*B][3072] fp16
            const unsigned short* __restrict__ WhhT,   // [2560][512] bf16
            const float* __restrict__ bias_l,
            const int* __restrict__ lens,
            unsigned short* __restrict__ Hxb,          // [2][64][512] bf16
            int* __restrict__ flags,                   // [4][32] ints
            unsigned short* __restrict__ xdst,         // bf16 (T,B,H), null on last layer
            float* __restrict__ dout,                  // fp32 (B,T,H), last layer only
            int rev)
{
  __shared__ __align__(16) unsigned short Al[16*HSTR];
  __shared__ float gl[64*GLP];
  __shared__ float bl[80];
  __shared__ int ll[16];
  __shared__ __align__(8) unsigned short hl[256];

  const int tid = threadIdx.x;
  const int bt  = blockIdx.x & (BT_GROUPS-1);
  const int g   = blockIdx.x >> 2;                     // 0..31
  const int lane = tid & 63, wv = tid >> 6;
  const int frow = lane & 15, quad = lane >> 4;

  for(int i=tid;i<80;i+=SCAN_THREADS) bl[i] = bias_l[(i>>4)*HID + g*16 + (i&15)];
  if(tid<16) ll[tid] = lens[bt*16+tid];
  __syncthreads();

  // register-resident W_hh fragments: 5 gate tiles x 4 ksteps (kstep = wv + 4j)
  bf16x8 Bf[5][4];
  #pragma unroll
  for(int q=0;q<5;q++)
    #pragma unroll
    for(int j=0;j<4;j++)
      Bf[q][j] = *(const bf16x8*)(WhhT + (size_t)(q*HID + g*16 + frow)*HID + (wv + j*4)*32 + quad*8);

  // combine constants: each thread owns one (row, col)
  const int cr = tid >> 4;           // 0..15
  const int jj = tid & 15;           // 0..15
  const int brow_g = bt*16 + cr;
  const int hcol   = g*16 + jj;
  const int L_r = ll[cr];
  float cst=0.f, hs=0.f;
  unsigned short hbf=0; int tprev=0;

  for(int s=0; s<T_STEPS; s++){
    // ---- phase 1: publish h(s-1) [w0] | outputs [all] | poll peers [w1] ----
    if(s>0){
      if(wv==0){
        int r = lane>>2, c4 = (lane&3)*4;
        unsigned long long v = *(const unsigned long long*)(hl + r*16 + c4);
        const unsigned short* dst = Hxb + (size_t)(s&1)*BATCH*HID + (size_t)(bt*16+r)*HID + g*16 + c4;
        asm volatile("global_store_dwordx2 %0, %1, off sc0 sc1" :: "v"(dst), "v"(v) : "memory");
        asm volatile("s_waitcnt vmcnt(0)" ::: "memory");
        if(lane==0)
          __hip_atomic_store(flags + bt*GBLK + g, s, __ATOMIC_RELAXED, __HIP_MEMORY_SCOPE_AGENT);
      }
      if(dout) dout[((size_t)brow_g*T_STEPS + tprev)*HID + hcol] = hs;
      else     xdst[((size_t)tprev*BATCH + brow_g)*HID + hcol] = hbf;
      if(wv==1){
        const int* fpp = flags + bt*GBLK + (lane & (GBLK-1));
        int it = 0;
        while(1){
          int v = __hip_atomic_load(fpp, __ATOMIC_RELAXED, __HIP_MEMORY_SCOPE_AGENT);
          if(__all(v >= s)) break;
          if(++it > (1<<20)) break;
        }
        asm volatile("" ::: "memory");
      }
    }
    __syncthreads();   // b1: h(s) visible to group

    // ---- phase 2: h loads (IC-coherent) + xi prefetch, then stage to LDS ----
    u32x4 hv[4];
    {
      const unsigned short* hbase = Hxb + (size_t)(s&1)*BATCH*HID + (size_t)bt*16*HID;
      #pragma unroll
      for(int i=0;i<4;i++){
        int idx = tid + i*256;
        const unsigned short* p = hbase + (size_t)(idx>>6)*HID + (idx&63)*8;
        asm volatile("global_load_dwordx4 %0, %1, off sc0 sc1" : "=v"(hv[i]) : "v"(p) : "memory");
      }
    }
    bool valid = s < L_r;
    int tcur = rev ? (valid ? (L_r-1-s) : s) : s;
    const fp16_t* xr = Xi + ((size_t)tcur*BATCH + brow_g)*GATES + hcol;
    fp16_t x0v=xr[0], x1v=xr[512], x2v=xr[1024], x3v=xr[1536], x4v=xr[2048], x5v=xr[2560];
    asm volatile("s_waitcnt vmcnt(0)" ::: "memory");
    #pragma unroll
    for(int i=0;i<4;i++){
      int idx = tid + i*256;
      *(u32x4*)(Al + (idx>>6)*HSTR + (idx&63)*8) = hv[i];
    }
    __syncthreads();  // b2: h staged

    // ---- phase 3: MFMAs (K split mod 4 across waves) + gate partials to LDS ----
    f32x4 acc[5];
    #pragma unroll
    for(int q=0;q<5;q++) acc[q] = (f32x4){0.f,0.f,0.f,0.f};
    #pragma unroll
    for(int j=0;j<4;j++){
      bf16x8 a = *(const bf16x8*)((const bf16_t*)Al + (size_t)frow*HSTR + (wv + j*4)*32 + quad*8);
      #pragma unroll
      for(int q=0;q<5;q++)
        acc[q] = __builtin_amdgcn_mfma_f32_16x16x32_bf16(a, Bf[q][j], acc[q],0,0,0);
    }
    #pragma unroll
    for(int q=0;q<5;q++)
      #pragma unroll
      for(int r4=0;r4<4;r4++)
        gl[(wv*16 + quad*4 + r4)*GLP + q*16 + frow] = acc[q][r4];   // C: col=lane&15, row=quad*4+reg
    __syncthreads();  // b3

    // ---- phase 4: combine (all 256 threads, 1 h-value each) ----
    {
      float ga[5];
      #pragma unroll
      for(int q=0;q<5;q++){
        float sum = bl[q*16+jj];
        #pragma unroll
        for(int w=0;w<4;w++) sum += gl[(w*16+cr)*GLP + q*16 + jj];
        ga[q] = sum;
      }
      ga[0] += (float)x0v; ga[1] += (float)x1v; ga[2] += (float)x2v;
      ga[3] += (float)x3v; ga[4] += (float)x4v;
      float m = valid ? 1.f : 0.f;
      float gi=sigm(ga[0]), gf=sigm(ga[1]), gcv=tanh_f(ga[2]), go=sigm(ga[3]), grv=sigm(ga[4]);
      cst = (gf*cst + gi*gcv) * m;
      hs  = (grv*(go*tanh_f(cst)) + (1.f-grv)*(float)x5v) * m;
      hbf = f2bf(hs);
      hl[cr*16+jj] = hbf;
      tprev = tcur;
    }
    __syncthreads();  // b4: hl complete
  }

  // epilogue: outputs for step T-1
  if(dout) dout[((size_t)brow_g*T_STEPS + tprev)*HID + hcol] = hs;
  else     xdst[((size_t)tprev*BATCH + brow_g)*HID + hcol] = hbf;
}

extern "C" void kernel_launch(void* const* d_in, const int* in_sizes, int n_in,
                              void* d_out, int out_size, void* d_ws, size_t ws_size,
                              hipStream_t stream){
  const float* inp    = (const float*)d_in[0];
  const float* weight = (const float*)d_in[1];
  const float* bias   = (const float*)d_in[2];
  const int*   lens   = (const int*)d_in[3];
  float* dout = (float*)d_out;

  char* ws = (char*)d_ws;
  size_t off = 0;
  const size_t WTL = (size_t)(3072+2560)*512;   // per-layer transposed bf16 elements
  unsigned short* WT = (unsigned short*)(ws+off); off += (size_t)NLAYERS*WTL*2;        // 23.1 MB
  unsigned short* x0 = (unsigned short*)(ws+off); off += (size_t)T_STEPS*BATCH*HID*2;  // 16.8 MB
  unsigned short* xA = (unsigned short*)(ws+off); off += (size_t)T_STEPS*BATCH*HID*2;  // 16.8 MB
  fp16_t* Xi = (fp16_t*)(ws+off); off += (size_t)T_STEPS*BATCH*GATES*2;                // 100.7 MB
  unsigned short* Hxb = (unsigned short*)(ws+off); off += (size_t)2*BATCH*HID*2;       // 128 KB
  int* flags = (int*)(ws+off); off += 512;

  const size_t WS_L = (size_t)512*3072 + (size_t)512*2560; // per-layer fp32 weight elements
  for(int l=0;l<NLAYERS;l++){
    const float* wih = weight + l*WS_L;
    const float* whh = wih + (size_t)512*3072;
    unsigned short* wihT = WT + l*WTL;
    unsigned short* whhT = wihT + (size_t)3072*512;
    transpose_cast_kernel<<<dim3(3072/32,512/32),256,0,stream>>>(wih, wihT, 512, 3072);
    transpose_cast_kernel<<<dim3(2560/32,512/32),256,0,stream>>>(whh, whhT, 512, 2560);
  }
  prep_x0_kernel<<<8192,256,0,stream>>>(inp, lens, x0);

  const unsigned short* bufs_in[4]  = {x0, xA, x0, xA};
  unsigned short*       bufs_out[4] = {xA, x0, xA, nullptr};
  for(int l=0;l<NLAYERS;l++){
    xi_gemm_kernel<<<dim3(128,24),256,0,stream>>>(bufs_in[l], WT + l*WTL, Xi);
    hipMemsetAsync(Hxb, 0, (size_t)2*BATCH*HID*2 + 512, stream);  // Hxb + flags (adjacent)
    scan_kernel<<<BT_GROUPS*GBLK, SCAN_THREADS, 0, stream>>>(
        Xi, WT + l*WTL + (size_t)3072*512,
        bias + (size_t)l*2560, lens, Hxb, flags,
        bufs_out[l], (l==3) ? dout : nullptr, l&1);
  }
}